// Round 12
// baseline (507.780 us; speedup 1.0000x reference)
//
#include <hip/hip_runtime.h>
#include <stdint.h>

static constexpr int NT = 26000;   // n_terms
static constexpr int NE = 120000;  // n_edges

typedef __attribute__((ext_vector_type(8))) short short8;   // 8 bf16 (MFMA A/B frag)
typedef __attribute__((ext_vector_type(4))) float f32x4;    // MFMA C/D frag
typedef __attribute__((ext_vector_type(4))) unsigned int u32x4;

static constexpr int SCS = 52004;  // per-chunk scale-array stride (floats); sentinel at [52000..52001]

__device__ __forceinline__ int rfl(int v){ return __builtin_amdgcn_readfirstlane(v); }

__device__ __forceinline__ uint32_t f2b(float f){ union{float f; uint32_t u;} a; a.f=f; return (a.u + 0x7fffu + ((a.u>>16)&1u))>>16; }

__device__ __forceinline__ void nts4(uint8_t* p, uint32_t a, uint32_t b, uint32_t c, uint32_t d){
  u32x4 v; v.x=a; v.y=b; v.z=c; v.w=d;
  __builtin_nontemporal_store(v, reinterpret_cast<u32x4*>(p));
}

// ---------- CSR build ----------
__global__ __launch_bounds__(256) void k_zero_deg(int* __restrict__ deg){
  int i = blockIdx.x*256 + threadIdx.x;
  if (i < NT) deg[i] = 0;
}
__global__ __launch_bounds__(256) void k_count(const int* __restrict__ ei, int* __restrict__ deg){
  int e = blockIdx.x*256 + threadIdx.x;
  if (e < NE) atomicAdd(&deg[ei[e]], 1);
}
// slots = max(4, ceil4(deg)); rp = prefix(slots); cur = rp
__global__ __launch_bounds__(1024) void k_scan(const int* __restrict__ deg, int* __restrict__ rp,
                                               int* __restrict__ cur){
  __shared__ int part[1024];
  const int t = threadIdx.x;
  const int CH = (NT + 1023)/1024;   // 26
  const int base = t*CH;
  int sum = 0;
  for (int i=0;i<CH;i++){
    int idx=base+i;
    if (idx<NT){ int d = deg[idx]; sum += (d<=4)?4:((d+3)&~3); }
  }
  part[t] = sum;
  __syncthreads();
  for (int off=1; off<1024; off<<=1){
    int v = (t>=off) ? part[t-off] : 0;
    __syncthreads();
    part[t] += v;
    __syncthreads();
  }
  int run = (t==0) ? 0 : part[t-1];
  for (int i=0;i<CH;i++){
    int idx = base+i;
    if (idx<NT){
      int d = deg[idx];
      int slot = (d<=4)?4:((d+3)&~3);
      rp[idx] = run; cur[idx] = run;
      run += slot;
    }
  }
  if (t==1023) rp[NT] = part[1023];
}
// init: zero page; cols sentinels (112004 u32); cols2 sentinels (208000 u32); scale sentinels
__global__ __launch_bounds__(256) void k_init(uint32_t* __restrict__ zp, uint32_t* __restrict__ cols32,
                                              uint32_t* __restrict__ cols2_32,
                                              float* __restrict__ scP, float* __restrict__ scQ,
                                              float* __restrict__ scY){
  int i = blockIdx.x*256 + threadIdx.x;
  if (i < 1024) zp[i] = 0;
  else if (i < 113028) cols32[i-1024] = 0x65906590u;        // 26000 | 26000<<16
  else if (i < 321028) cols2_32[i-113028] = 0x65906590u;
  if (i < 4){
    int ch = i>>1, j = i&1;
    scP[ch*SCS + NT*2 + j] = 0.f;
    scQ[ch*SCS + NT*2 + j] = 0.f;
    scY[ch*SCS + NT*2 + j] = 0.f;
  }
}
__global__ __launch_bounds__(256) void k_fill(const int* __restrict__ ei, int* __restrict__ cur,
                                              const int* __restrict__ rp,
                                              uint16_t* __restrict__ cols, uint16_t* __restrict__ cols2){
  int e = blockIdx.x*256 + threadIdx.x;
  if (e < NE){
    int r = ei[e];
    int pos = atomicAdd(&cur[r], 1);
    int slot = pos - rp[r];
    uint16_t c = (uint16_t)ei[NE + e];
    if (slot < 16) cols2[r*16 + slot] = c;
    else           cols[pos] = c;
  }
}
// pre-pack weights to bf16 [COUT][CIN] row-major, zero-padded K
__global__ __launch_bounds__(256) void k_prepw(const float* __restrict__ W1, const float* __restrict__ W2,
                                               const float* __restrict__ W3,
                                               uint16_t* __restrict__ Wt1, uint16_t* __restrict__ Wt2,
                                               uint16_t* __restrict__ Wt3){
  for (int idx = threadIdx.x; idx < 8192; idx += 256){
    if (idx < 2048){           // W1: 64 x 22 -> [64][32]
      int o = idx >> 5, k = idx & 31;
      Wt1[idx] = (uint16_t)((k < 22) ? f2b(W1[o*22 + k]) : 0);
    } else if (idx < 6144){    // W2: 64 x 64
      int j = idx - 2048;
      Wt2[j] = (uint16_t)f2b(W2[j]);
    } else {                   // W3: 32 x 64
      int j = idx - 6144;
      Wt3[j] = (uint16_t)f2b(W3[j]);
    }
  }
}

// ---------- build h0 as biased-u8: per chunk [NT][2 half][16 row][32 ch] = 1KB; scP per (node,half) ----------
__global__ __launch_bounds__(256) void k_build_h0(const float* __restrict__ x, const int* __restrict__ tidx,
                                                  const float* __restrict__ emb,
                                                  uint8_t* __restrict__ p8, float* __restrict__ scP){
  __shared__ float red[2][16][16];
  __shared__ float sinv[2][16];
  const int nb16 = NT/16;                       // 1625
  const int ch = (blockIdx.x >= nb16) ? 1 : 0;
  const int bi = blockIdx.x - ch*nb16;
  const float* xc = x + (size_t)ch*32*NT*14;
  uint8_t* p8c = p8 + (size_t)ch*NT*1024;
  float* scc = scP + (size_t)ch*SCS;

  const int t  = threadIdx.x;
  const int ni = t & 15;
  const int n  = bi*16 + ni;
  const int r  = t >> 4;
  const float* er = emb + (size_t)tidx[n]*8;
  float ev[8];
  #pragma unroll
  for (int i=0;i<8;i++) ev[i]=er[i];

  float v[2][32];
  #pragma unroll
  for (int rt=0; rt<2; rt++){
    const int b = r + rt*16;
    const float* xr = xc + ((size_t)b*NT + n)*14;
    float m = 0.f;
    #pragma unroll
    for (int i=0;i<14;i++){ float a=xr[i]; v[rt][i]=a; m=fmaxf(m,fabsf(a)); }
    #pragma unroll
    for (int i=0;i<8;i++){ float a=ev[i]; v[rt][14+i]=a; m=fmaxf(m,fabsf(a)); }
    #pragma unroll
    for (int i=22;i<32;i++) v[rt][i]=0.f;
    red[rt][r][ni] = m;
  }
  __syncthreads();
  if (t < 32){
    int rt = t >> 4, nn = t & 15;
    float mm = 0.f;
    #pragma unroll
    for (int i=0;i<16;i++) mm = fmaxf(mm, red[rt][i][nn]);
    sinv[rt][nn] = (mm > 0.f) ? 127.0f/mm : 0.f;
    scc[(size_t)(bi*16+nn)*2 + rt] = mm * (1.0f/127.0f);
  }
  __syncthreads();

  uint8_t* dst = p8c + (size_t)n*1024;
  #pragma unroll
  for (int rt=0; rt<2; rt++){
    const float inv = sinv[rt][ni];
    uint32_t pk[8];
    #pragma unroll
    for (int u=0;u<8;u++){
      uint32_t w = 0;
      #pragma unroll
      for (int j=0;j<4;j++){
        int q = __float2int_rn(v[rt][u*4+j]*inv) + 128;
        q = q < 0 ? 0 : (q > 255 ? 255 : q);
        w |= (uint32_t)q << (8*j);
      }
      pk[u] = w;
    }
    nts4(dst + rt*512 + r*32,      pk[0],pk[1],pk[2],pk[3]);
    nts4(dst + rt*512 + r*32 + 16, pk[4],pk[5],pk[6],pk[7]);
  }
}

// ---------- quantized gather machinery ----------
template<int KS> struct VecT;
template<> struct VecT<2>{ using T = uint4; };
template<> struct VecT<1>{ using T = uint2; };

__device__ __forceinline__ void dq_u(float* a, uint32_t u, float s){
  a[0] += s*(float)(u & 0xffu);
  a[1] += s*(float)((u>>8) & 0xffu);
  a[2] += s*(float)((u>>16) & 0xffu);
  a[3] += s*(float)(u>>24);
}
__device__ __forceinline__ void dq_s(float* a, uint32_t u, float s){
  a[0] += s*(float)(int8_t)(u & 0xff);
  a[1] += s*(float)(int8_t)((u>>8) & 0xff);
  a[2] += s*(float)(int8_t)((u>>16) & 0xff);
  a[3] += s*(float)(int8_t)(u>>24);
}
template<int KS, bool SG>
__device__ __forceinline__ void dqv(float (&acc)[KS][8], const typename VecT<KS>::T& v, float s){
  if constexpr (KS==2){
    if constexpr (SG){ dq_s(&acc[0][0],v.x,s); dq_s(&acc[0][4],v.y,s); dq_s(&acc[1][0],v.z,s); dq_s(&acc[1][4],v.w,s); }
    else             { dq_u(&acc[0][0],v.x,s); dq_u(&acc[0][4],v.y,s); dq_u(&acc[1][0],v.z,s); dq_u(&acc[1][4],v.w,s); }
  } else {
    if constexpr (SG){ dq_s(&acc[0][0],v.x,s); dq_s(&acc[0][4],v.y,s); }
    else             { dq_u(&acc[0][0],v.x,s); dq_u(&acc[0][4],v.y,s); }
  }
}

// Depth-8 prologue-resident aggregate over fixed-slot cols2 (16/node) + rare CSR overflow.
// MODE: 0 = unsigned u8, 1 = biased u8 (track sumS), 2 = signed i8.
// Sentinel col NT has scale 0 -> pad slots contribute exactly 0 (no conditionals needed).
template<int KS, int STRB, int MODE>
__device__ __forceinline__ float aggregate8(float (&acc)[KS][8], float& sumS,
    const uint8_t* __restrict__ hin, const uint8_t* __restrict__ zp8,
    const float* __restrict__ sc,
    const int* __restrict__ deg, const int* __restrict__ rp,
    const uint16_t* __restrict__ cols, const uint16_t* __restrict__ cols2,
    int node, uint32_t offB, int rt)
{
  using V = typename VecT<KS>::T;
  constexpr bool SG = (MODE==2);
  auto bp = [&](int c)->const uint8_t*{ return (c < NT) ? (hin + (size_t)c*STRB) : zp8; };

  // level 1: all independent
  const uint4 cc0 = *reinterpret_cast<const uint4*>(cols2 + node*16);
  const uint4 cc1 = *reinterpret_cast<const uint4*>(cols2 + node*16 + 8);
  const int dg = rfl(deg[node]);
  V ow = *reinterpret_cast<const V*>(hin + (size_t)node*STRB + offB);
  const float so = sc[node*2+rt];

  // level 2: 8 gathers + scales, all issued together
  int c0 = rfl(cc0.x)&0xffff, c1 = (rfl(cc0.x)>>16)&0xffff;
  int c2 = rfl(cc0.y)&0xffff, c3 = (rfl(cc0.y)>>16)&0xffff;
  int c4 = rfl(cc0.z)&0xffff, c5 = (rfl(cc0.z)>>16)&0xffff;
  int c6 = rfl(cc0.w)&0xffff, c7 = (rfl(cc0.w)>>16)&0xffff;
  V v0 = *reinterpret_cast<const V*>(bp(c0)+offB); float s0 = sc[c0*2+rt];
  V v1 = *reinterpret_cast<const V*>(bp(c1)+offB); float s1 = sc[c1*2+rt];
  V v2 = *reinterpret_cast<const V*>(bp(c2)+offB); float s2 = sc[c2*2+rt];
  V v3 = *reinterpret_cast<const V*>(bp(c3)+offB); float s3 = sc[c3*2+rt];
  V v4 = *reinterpret_cast<const V*>(bp(c4)+offB); float s4 = sc[c4*2+rt];
  V v5 = *reinterpret_cast<const V*>(bp(c5)+offB); float s5 = sc[c5*2+rt];
  V v6 = *reinterpret_cast<const V*>(bp(c6)+offB); float s6 = sc[c6*2+rt];
  V v7 = *reinterpret_cast<const V*>(bp(c7)+offB); float s7 = sc[c7*2+rt];

  const float degf = (dg > 1) ? (float)dg : 1.0f;
  #pragma unroll
  for (int ks=0;ks<KS;ks++)
    #pragma unroll
    for (int j=0;j<8;j++) acc[ks][j]=0.f;
  dqv<KS,SG>(acc, ow, so*degf);
  if constexpr (MODE==1) sumS = so*degf;

  dqv<KS,SG>(acc, v0, s0); dqv<KS,SG>(acc, v1, s1);
  dqv<KS,SG>(acc, v2, s2); dqv<KS,SG>(acc, v3, s3);
  if constexpr (MODE==1) sumS += s0+s1+s2+s3;
  if (dg > 4){
    dqv<KS,SG>(acc, v4, s4); dqv<KS,SG>(acc, v5, s5);
    dqv<KS,SG>(acc, v6, s6); dqv<KS,SG>(acc, v7, s7);
    if constexpr (MODE==1) sumS += s4+s5+s6+s7;
  }
  if (dg > 8){
    int c8  = rfl(cc1.x)&0xffff, c9  = (rfl(cc1.x)>>16)&0xffff;
    int c10 = rfl(cc1.y)&0xffff, c11 = (rfl(cc1.y)>>16)&0xffff;
    V w0 = *reinterpret_cast<const V*>(bp(c8)+offB);  float t0 = sc[c8*2+rt];
    V w1 = *reinterpret_cast<const V*>(bp(c9)+offB);  float t1 = sc[c9*2+rt];
    V w2 = *reinterpret_cast<const V*>(bp(c10)+offB); float t2 = sc[c10*2+rt];
    V w3 = *reinterpret_cast<const V*>(bp(c11)+offB); float t3 = sc[c11*2+rt];
    dqv<KS,SG>(acc, w0, t0); dqv<KS,SG>(acc, w1, t1);
    dqv<KS,SG>(acc, w2, t2); dqv<KS,SG>(acc, w3, t3);
    if constexpr (MODE==1) sumS += t0+t1+t2+t3;
    if (dg > 12){
      int c12 = rfl(cc1.z)&0xffff, c13 = (rfl(cc1.z)>>16)&0xffff;
      int c14 = rfl(cc1.w)&0xffff, c15 = (rfl(cc1.w)>>16)&0xffff;
      V y0 = *reinterpret_cast<const V*>(bp(c12)+offB); float u0 = sc[c12*2+rt];
      V y1 = *reinterpret_cast<const V*>(bp(c13)+offB); float u1 = sc[c13*2+rt];
      V y2 = *reinterpret_cast<const V*>(bp(c14)+offB); float u2 = sc[c14*2+rt];
      V y3 = *reinterpret_cast<const V*>(bp(c15)+offB); float u3 = sc[c15*2+rt];
      dqv<KS,SG>(acc, y0, u0); dqv<KS,SG>(acc, y1, u1);
      dqv<KS,SG>(acc, y2, u2); dqv<KS,SG>(acc, y3, u3);
      if constexpr (MODE==1) sumS += u0+u1+u2+u3;
      if (dg > 16){   // ultra-rare CSR overflow
        const int e0 = rfl(rp[node]);
        const int slots = (dg+3)&~3;
        for (int e = 16; e < slots; e += 4){
          uint2 cx = *reinterpret_cast<const uint2*>(cols + e0 + e);
          int d0 = rfl(cx.x)&0xffff, d1 = (rfl(cx.x)>>16)&0xffff;
          int d2 = rfl(cx.y)&0xffff, d3 = (rfl(cx.y)>>16)&0xffff;
          V z0 = *reinterpret_cast<const V*>(bp(d0)+offB); float q0 = sc[d0*2+rt];
          V z1 = *reinterpret_cast<const V*>(bp(d1)+offB); float q1 = sc[d1*2+rt];
          V z2 = *reinterpret_cast<const V*>(bp(d2)+offB); float q2 = sc[d2*2+rt];
          V z3 = *reinterpret_cast<const V*>(bp(d3)+offB); float q3 = sc[d3*2+rt];
          dqv<KS,SG>(acc, z0, q0); dqv<KS,SG>(acc, z1, q1);
          dqv<KS,SG>(acc, z2, q2); dqv<KS,SG>(acc, z3, q3);
          if constexpr (MODE==1) sumS += q0+q1+q2+q3;
        }
      }
    }
  }
  return 1.0f / degf;
}

// ---------- L1: gather(h0 u8-biased 32ch) -> relu GEMM(W1) -> Q u8-unsigned + scQ ----------
__global__ __launch_bounds__(256, 6) void k_layer1(
    const uint8_t* __restrict__ pin, const float* __restrict__ scP,
    uint8_t* __restrict__ qout, float* __restrict__ scQ,
    const int* __restrict__ deg, const int* __restrict__ rp,
    const uint16_t* __restrict__ cols, const uint16_t* __restrict__ cols2,
    const uint8_t* __restrict__ zp8,
    const uint16_t* __restrict__ Wt, const float* __restrict__ bias)
{
  const int t=threadIdx.x, lane=t&63, w=t>>6, l15=lane&15, lg=lane>>4;
  const int rt = w & 1;
  const int idx = blockIdx.x*2 + (w>>1);
  const int ch = (idx >= NT) ? 1 : 0;
  const int node = idx - ch*NT;
  const uint8_t* pc = pin + (size_t)ch*NT*1024;
  uint8_t* qc = qout + (size_t)ch*NT*2048;
  const float* scp = scP + (size_t)ch*SCS;
  float* scq = scQ + (size_t)ch*SCS;

  const uint32_t offB = (uint32_t)(rt*512 + l15*32 + lg*8);

  float acc[1][8]; float sumS = 0.f;
  const float di = aggregate8<1,1024,1>(acc, sumS, pc, zp8, scp, deg, rp, cols, cols2, node, offB, rt);
  const float corr = 128.0f * sumS;

  short8 bfrag;
  #pragma unroll
  for (int j=0;j<8;j++) bfrag[j] = (short)f2b((acc[0][j] - corr)*di);

  float av[4][4];
  float m = 0.f;
  #pragma unroll
  for (int ot=0;ot<4;ot++){
    const int o0 = ot*16;
    short8 af = *reinterpret_cast<const short8*>(Wt + (o0 + l15)*32 + lg*8);
    f32x4 d = *reinterpret_cast<const f32x4*>(bias + o0 + lg*4);
    d = __builtin_amdgcn_mfma_f32_16x16x32_bf16(af, bfrag, d, 0,0,0);
    #pragma unroll
    for (int j=0;j<4;j++){
      float v = fmaxf(d[j], 0.f);
      av[ot][j] = v;
      m = fmaxf(m, v);
    }
  }
  #pragma unroll
  for (int sh=1; sh<64; sh<<=1) m = fmaxf(m, __shfl_xor(m, sh, 64));
  const float inv = (m > 0.f) ? 255.0f/m : 0.f;

  uint8_t* base = qc + (size_t)node*2048 + rt*1024 + l15*64;
  #pragma unroll
  for (int ot=0;ot<4;ot++){
    uint32_t pk = 0;
    #pragma unroll
    for (int j=0;j<4;j++){
      int q = __float2int_rn(av[ot][j]*inv);
      q = q > 255 ? 255 : q;
      pk |= (uint32_t)q << (8*j);
    }
    uint32_t boff = ((((ot&1)<<1)|(lg>>1))<<4) + ((ot>>1)<<3) + ((lg&1)<<2);
    __builtin_nontemporal_store(pk, reinterpret_cast<uint32_t*>(base + boff));
  }
  if (lane == 0) scq[node*2+rt] = m * (1.0f/255.0f);
}

// ---------- L2+G3 fused: gather(Q u8 64ch) -> relu GEMM(W2) -> LDS transpose -> GEMM(W3) -> Y3 i8 ----------
__global__ __launch_bounds__(256, 4) void k_l2g3(
    const uint8_t* __restrict__ qin, const float* __restrict__ scQ,
    uint8_t* __restrict__ yout, float* __restrict__ scY,
    const int* __restrict__ deg, const int* __restrict__ rp,
    const uint16_t* __restrict__ cols, const uint16_t* __restrict__ cols2,
    const uint8_t* __restrict__ zp8,
    const uint16_t* __restrict__ Wt2, const float* __restrict__ bias,
    const uint16_t* __restrict__ Wt3)
{
  __shared__ uint32_t lt[4*512];
  const int t=threadIdx.x, lane=t&63, w=t>>6, l15=lane&15, lg=lane>>4;
  const int rt = w & 1;
  const int idx = blockIdx.x*2 + (w>>1);
  const int ch = (idx >= NT) ? 1 : 0;
  const int node = idx - ch*NT;
  const uint8_t* qc = qin + (size_t)ch*NT*2048;
  uint8_t* yc = yout + (size_t)ch*NT*1024;
  const float* scq = scQ + (size_t)ch*SCS;
  float* scy = scY + (size_t)ch*SCS;

  const uint32_t offB = (uint32_t)(rt*1024 + l15*64 + lg*16);

  float acc[2][8]; float dummy;
  const float di = aggregate8<2,2048,0>(acc, dummy, qc, zp8, scq, deg, rp, cols, cols2, node, offB, rt);

  short8 bfrag[2];
  #pragma unroll
  for (int ks=0;ks<2;ks++){
    short8 bf;
    #pragma unroll
    for (int j=0;j<8;j++) bf[j] = (short)f2b(acc[ks][j]*di);
    bfrag[ks]=bf;
  }

  // GEMM1: h2 = relu(W2 * s^T + b2) -> LDS tiled (bf16)
  uint32_t* L = lt + w*512;
  #pragma unroll
  for (int ot=0;ot<4;ot++){
    const int o0 = ot*16;
    short8 af0 = *reinterpret_cast<const short8*>(Wt2 + (o0 + l15)*64 + lg*8);
    short8 af1 = *reinterpret_cast<const short8*>(Wt2 + (o0 + l15)*64 + 32 + lg*8);
    f32x4 d = *reinterpret_cast<const f32x4*>(bias + o0 + lg*4);
    d = __builtin_amdgcn_mfma_f32_16x16x32_bf16(af0, bfrag[0], d, 0,0,0);
    d = __builtin_amdgcn_mfma_f32_16x16x32_bf16(af1, bfrag[1], d, 0,0,0);
    float a0=fmaxf(d[0],0.f), a1=fmaxf(d[1],0.f), a2=fmaxf(d[2],0.f), a3=fmaxf(d[3],0.f);
    *reinterpret_cast<uint2*>(L + ot*128 + l15*8 + lg*2) =
        make_uint2(f2b(a0) | (f2b(a1)<<16), f2b(a2) | (f2b(a3)<<16));
  }

  short8 b3f[2];
  #pragma unroll
  for (int ks=0;ks<2;ks++)
    b3f[ks] = *reinterpret_cast<const short8*>(L + (ks*2+(lg>>1))*128 + l15*8 + (lg&1)*4);

  // GEMM2: Y3 = W3 * h2^T -> signed i8 quantize
  float dd[2][4];
  float m = 0.f;
  #pragma unroll
  for (int ot=0;ot<2;ot++){
    const int o0 = ot*16;
    short8 af0 = *reinterpret_cast<const short8*>(Wt3 + (o0 + l15)*64 + lg*8);
    short8 af1 = *reinterpret_cast<const short8*>(Wt3 + (o0 + l15)*64 + 32 + lg*8);
    f32x4 d = {0.f,0.f,0.f,0.f};
    d = __builtin_amdgcn_mfma_f32_16x16x32_bf16(af0, b3f[0], d, 0,0,0);
    d = __builtin_amdgcn_mfma_f32_16x16x32_bf16(af1, b3f[1], d, 0,0,0);
    #pragma unroll
    for (int j=0;j<4;j++){
      dd[ot][j] = d[j];
      m = fmaxf(m, fabsf(d[j]));
    }
  }
  #pragma unroll
  for (int sh=1; sh<64; sh<<=1) m = fmaxf(m, __shfl_xor(m, sh, 64));
  const float inv = (m > 0.f) ? 127.0f/m : 0.f;

  uint8_t* base = yc + (size_t)node*1024 + rt*512 + l15*32;
  #pragma unroll
  for (int ot=0;ot<2;ot++){
    uint32_t pk = 0;
    #pragma unroll
    for (int j=0;j<4;j++){
      int q = __float2int_rn(dd[ot][j]*inv);
      pk |= (uint32_t)(q & 0xff) << (8*j);
    }
    uint32_t boff = (((ot<<1)|(lg>>1))<<3) + ((lg&1)<<2);
    __builtin_nontemporal_store(pk, reinterpret_cast<uint32_t*>(base + boff));
  }
  if (lane == 0) scy[node*2+rt] = m * (1.0f/127.0f);
}

// ---------- final: aggregate Y3 (i8 32ch) + b3 + relu + head dot + sigmoid ----------
__global__ __launch_bounds__(256, 6) void k_fin(
    const uint8_t* __restrict__ yin, const float* __restrict__ scY,
    const int* __restrict__ deg, const int* __restrict__ rp,
    const uint16_t* __restrict__ cols, const uint16_t* __restrict__ cols2,
    const uint8_t* __restrict__ zp8,
    const float* __restrict__ b3, const float* __restrict__ Wo, const float* __restrict__ bo,
    float* __restrict__ tmp)            // [2][NT][32] f32
{
  const int t=threadIdx.x, lane=t&63, w=t>>6, l15=lane&15, lg=lane>>4;
  const int rt = w & 1;
  const int idx = blockIdx.x*2 + (w>>1);
  const int ch = (idx >= NT) ? 1 : 0;
  const int node = idx - ch*NT;
  const uint8_t* yc = yin + (size_t)ch*NT*1024;
  const float* scy = scY + (size_t)ch*SCS;

  const uint32_t offB = (uint32_t)(rt*512 + l15*32 + lg*8);

  float acc[1][8]; float dummy;
  const float di = aggregate8<1,1024,2>(acc, dummy, yc, zp8, scy, deg, rp, cols, cols2, node, offB, rt);

  const int k0 = lg*8;
  f32x4 bA = *reinterpret_cast<const f32x4*>(b3 + k0);
  f32x4 bB = *reinterpret_cast<const f32x4*>(b3 + k0 + 4);
  f32x4 wA = *reinterpret_cast<const f32x4*>(Wo + k0);
  f32x4 wB = *reinterpret_cast<const f32x4*>(Wo + k0 + 4);
  float z = 0.f;
  #pragma unroll
  for (int j=0;j<4;j++){
    z += fmaxf(acc[0][j]  *di + bA[j], 0.f) * wA[j];
    z += fmaxf(acc[0][4+j]*di + bB[j], 0.f) * wB[j];
  }
  z += __shfl_xor(z, 16, 64);
  z += __shfl_xor(z, 32, 64);
  if (lg == 0){
    float sg = 1.f/(1.f + expf(-(z + bo[0])));
    tmp[(size_t)ch*NT*32 + (size_t)node*32 + rt*16 + l15] = sg;
  }
}

// ---------- transpose tmp [2][NT][32] -> out [64][NT] ----------
__global__ __launch_bounds__(256) void k_tr(const float* __restrict__ tmp, float* __restrict__ out){
  const int nb = (NT + 255)/256;   // 102
  const int ch = (blockIdx.x >= nb) ? 1 : 0;
  const int bi = blockIdx.x - ch*nb;
  int n = bi*256 + threadIdx.x;
  if (n < NT){
    const float* tc = tmp + (size_t)ch*NT*32;
    float* oc = out + (size_t)ch*32*NT;
    f32x4 r[8];
    #pragma unroll
    for (int q=0;q<8;q++) r[q] = *reinterpret_cast<const f32x4*>(tc + (size_t)n*32 + q*4);
    #pragma unroll
    for (int q=0;q<8;q++)
      #pragma unroll
      for (int j=0;j<4;j++)
        oc[(size_t)(q*4+j)*NT + n] = r[q][j];
  }
}

// ---------- workspace layout (bytes); ~169.3 MB (<= 213,784,016 proven) ----------
static constexpr size_t OFF_P     = 0;              // h0 u8 [2][NT][1024] (Y3 aliases)
static constexpr size_t OFF_Q     = 53248000;       // Q u8 [2][NT][2048]
static constexpr size_t OFF_TMP   = 159744000;      // [2][NT][32] f32
static constexpr size_t OFF_ZP    = 166400000;      // 4 KB zero page
static constexpr size_t OFF_WT1   = 166404096;
static constexpr size_t OFF_WT2   = 166408192;
static constexpr size_t OFF_WT3   = 166416384;
static constexpr size_t OFF_SCP   = 166420480;      // [2][SCS] f32 = 416,032
static constexpr size_t OFF_SCQ   = 166836512;
static constexpr size_t OFF_SCY   = 167252544;
static constexpr size_t OFF_DEG   = 167668576;
static constexpr size_t OFF_RP    = 167772576;
static constexpr size_t OFF_CUR   = 167876592;
static constexpr size_t OFF_COLS  = 167980592;      // 224008 u16 (incl sentinels)
static constexpr size_t OFF_COLS2 = 168428608;      // NT*16 u16 = 832,000
static constexpr size_t WS_NEED   = 169260608;

extern "C" void kernel_launch(void* const* d_in, const int* in_sizes, int n_in,
                              void* d_out, int out_size, void* d_ws, size_t ws_size,
                              hipStream_t stream)
{
  const float* x    = (const float*)d_in[0];
  const int*   ei   = (const int*)  d_in[1];
  const int*   tidx = (const int*)  d_in[2];
  const float* emb  = (const float*)d_in[3];
  const float* W1   = (const float*)d_in[4];
  const float* b1   = (const float*)d_in[5];
  const float* W2   = (const float*)d_in[6];
  const float* b2   = (const float*)d_in[7];
  const float* W3   = (const float*)d_in[8];
  const float* b3   = (const float*)d_in[9];
  const float* Wo   = (const float*)d_in[10];
  const float* bo   = (const float*)d_in[11];
  float* out = (float*)d_out;

  if (ws_size < WS_NEED) return;

  char* ws = (char*)d_ws;
  uint8_t*  P     = (uint8_t*) (ws + OFF_P);
  uint8_t*  Y3    = (uint8_t*) (ws + OFF_P);     // aliases P (h0 dead after layer1)
  uint8_t*  Q     = (uint8_t*) (ws + OFF_Q);
  float*    tmpf  = (float*)   (ws + OFF_TMP);
  uint32_t* zp    = (uint32_t*)(ws + OFF_ZP);
  uint8_t*  zp8   = (uint8_t*) (ws + OFF_ZP);
  uint16_t* Wt1   = (uint16_t*)(ws + OFF_WT1);
  uint16_t* Wt2   = (uint16_t*)(ws + OFF_WT2);
  uint16_t* Wt3   = (uint16_t*)(ws + OFF_WT3);
  float*    scP   = (float*)   (ws + OFF_SCP);
  float*    scQ   = (float*)   (ws + OFF_SCQ);
  float*    scY   = (float*)   (ws + OFF_SCY);
  int*      deg   = (int*)     (ws + OFF_DEG);
  int*      rp    = (int*)     (ws + OFF_RP);
  int*      cur   = (int*)     (ws + OFF_CUR);
  uint16_t* cols  = (uint16_t*)(ws + OFF_COLS);
  uint16_t* cols2 = (uint16_t*)(ws + OFF_COLS2);

  k_zero_deg<<<(NT+255)/256, 256, 0, stream>>>(deg);
  k_count   <<<(NE+255)/256, 256, 0, stream>>>(ei, deg);
  k_scan    <<<1, 1024, 0, stream>>>(deg, rp, cur);
  k_init    <<<1255, 256, 0, stream>>>(zp, (uint32_t*)cols, (uint32_t*)cols2, scP, scQ, scY);
  k_fill    <<<(NE+255)/256, 256, 0, stream>>>(ei, cur, rp, cols, cols2);
  k_prepw   <<<1, 256, 0, stream>>>(W1, W2, W3, Wt1, Wt2, Wt3);

  k_build_h0<<<2*(NT/16), 256, 0, stream>>>(x, tidx, emb, P, scP);
  k_layer1  <<<NT, 256, 0, stream>>>(P, scP, Q, scQ, deg, rp, cols, cols2, zp8, Wt1, b1);
  k_l2g3    <<<NT, 256, 0, stream>>>(Q, scQ, Y3, scY, deg, rp, cols, cols2, zp8, Wt2, b2, Wt3);
  k_fin     <<<NT, 256, 0, stream>>>(Y3, scY, deg, rp, cols, cols2, zp8, b3, Wo, bo, tmpf);
  k_tr      <<<2*((NT+255)/256), 256, 0, stream>>>(tmpf, out);
}